// Round 11
// baseline (140.071 us; speedup 1.0000x reference)
//
#include <hip/hip_runtime.h>

typedef unsigned short u16;
typedef float  f32x4  __attribute__((ext_vector_type(4)));
typedef float  f32x16 __attribute__((ext_vector_type(16)));
typedef short  s16x8  __attribute__((ext_vector_type(8)));
typedef unsigned int u32x2 __attribute__((ext_vector_type(2)));
typedef unsigned int u32x4 __attribute__((ext_vector_type(4)));

union U8 { u32x4 u; u32x2 u2[2]; s16x8 s; unsigned int uw[4]; };

// f32 -> bf16 bits, RTNE (inputs have no NaN/Inf)
__device__ __forceinline__ u16 f2bs(float f) {
    union { float f; unsigned int u; } x; x.f = f;
    return (u16)((x.u + 0x7FFFu + ((x.u >> 16) & 1u)) >> 16);
}

// packed RTNE f32x2 -> bf16x2
__device__ __forceinline__ unsigned int cvtpk(float a, float b) {
    unsigned int r;
    asm("v_cvt_pk_bf16_f32 %0, %1, %2" : "=v"(r) : "v"(a), "v"(b));
    return r;
}

#if __has_builtin(__builtin_amdgcn_exp2f)
#define EXP2(v) __builtin_amdgcn_exp2f(v)
#else
#define EXP2(v) exp2f(v)
#endif

__device__ __forceinline__ f32x4 mfma16(s16x8 a, s16x8 b, f32x4 c) {
    return __builtin_amdgcn_mfma_f32_16x16x32_bf16(a, b, c, 0, 0, 0);
}
__device__ __forceinline__ f32x16 mfma32(s16x8 a, s16x8 b, f32x16 c) {
    return __builtin_amdgcn_mfma_f32_32x32x16_bf16(a, b, c, 0, 0, 0);
}

// async global -> LDS, 16B per lane; lds base must be wave-uniform (HW adds lane*16)
typedef __attribute__((address_space(3))) unsigned int lds_u32;
typedef const __attribute__((address_space(1))) unsigned int glb_u32;
__device__ __forceinline__ void gl16(const u16* g, u16* l) {
    __builtin_amdgcn_global_load_lds((glb_u32*)g, (lds_u32*)l, 16, 0, 0);
}

#define VMW8  asm volatile("s_waitcnt vmcnt(8)" ::: "memory")
#define VMW0  asm volatile("s_waitcnt vmcnt(0)" ::: "memory")
#define LKW0  asm volatile("s_waitcnt lgkmcnt(0)" ::: "memory")
#define SB0   __builtin_amdgcn_sched_barrier(0)

// ---------------- pack weights via LDS transpose
__global__ __launch_bounds__(256) void pack_w2(const float* __restrict__ Wq,
                                               const float* __restrict__ Wk,
                                               const float* __restrict__ Wv,
                                               const float* __restrict__ Wo,
                                               u16* __restrict__ Wt) {
    __shared__ float tile[64][65];
    const int bid = blockIdx.x, tid = threadIdx.x;
    const float* src; u16* dst; int src_ld, sr0, sc0;
    if (bid < 108) {
        int tensor = bid / 36, rem = bid % 36, h = rem / 6, ct = rem % 6;
        const float* W = (tensor == 0) ? Wq : (tensor == 1) ? Wk : Wv;
        src = W + h * 24576; src_ld = 64; sr0 = ct * 64; sc0 = 0;
        dst = Wt + tensor * 147456 + h * 24576;
    } else {
        int rem = bid - 108, et = rem / 6, ft = rem % 6;
        src = Wo; src_ld = 384; sr0 = ft * 64; sc0 = et * 64;
        dst = Wt + 3 * 147456;
    }
    const int r = tid >> 2, cb = (tid & 3) * 16;
    const float* sp = src + (size_t)(sr0 + r) * src_ld + sc0 + cb;
    #pragma unroll
    for (int j = 0; j < 4; ++j)
        *(f32x4*)&tile[r][cb + j * 4] = *(const f32x4*)(sp + j * 4);
    __syncthreads();
    struct alignas(16) OV { u16 v[16]; } ov;
    #pragma unroll
    for (int j = 0; j < 16; ++j) ov.v[j] = f2bs(tile[cb + j][r]);
    u16* dp = dst + (size_t)(sc0 + r) * 384 + sr0 + cb;
    *(u32x4*)dp       = *(u32x4*)&ov.v[0];
    *(u32x4*)(dp + 8) = *(u32x4*)&ov.v[8];
}

// ---------------- x fp32 -> bf16
__global__ __launch_bounds__(256) void convert_x(const float* __restrict__ x, u16* __restrict__ xb) {
    const int i = (blockIdx.x * 256 + threadIdx.x) * 8;
    f32x4 a = *(const f32x4*)(x + i);
    f32x4 b = *(const f32x4*)(x + i + 4);
    U8 o;
    #pragma unroll
    for (int j = 0; j < 4; ++j) { o.s[j] = (short)f2bs(a[j]); o.s[4 + j] = (short)f2bs(b[j]); }
    *(u32x4*)(xb + i) = o.u;
}

// ---------------- QKV projection: xb[8192,384] @ Wt^T -> Qb/Kb/Vb [bh][t][64] bf16
__global__ __launch_bounds__(256) void proj2(const u16* __restrict__ xb,
                                             const u16* __restrict__ Wt,
                                             u16* __restrict__ Qb,
                                             u16* __restrict__ Kb,
                                             u16* __restrict__ Vb) {
    __shared__ u16 As[2][128 * 32];
    __shared__ u16 Bs[2][128 * 32];
    const int tid = threadIdx.x, w = tid >> 6, lane = tid & 63;
    const int lr = lane & 15, lg = lane >> 4;
    const int wr = w >> 1, wc = w & 1;
    const int mt = blockIdx.x, nt = blockIdx.y;          // grid (64, 9)
    const int m0 = mt * 128, n0 = nt * 128;

    const int c0 = w * 2 * 64 + lane;
    const int ar0 = c0 >> 2, acc0 = c0 & 3;
    const int c1 = c0 + 64;
    const int ar1 = c1 >> 2, acc1 = c1 & 3;
    const u16* gA0 = xb + (size_t)(m0 + ar0) * 384 + acc0 * 8;
    const u16* gA1 = xb + (size_t)(m0 + ar1) * 384 + acc1 * 8;
    const u16* gB0 = Wt + (size_t)(n0 + ar0) * 384 + acc0 * 8;
    const u16* gB1 = Wt + (size_t)(n0 + ar1) * 384 + acc1 * 8;

    f32x4 acc[4][4];
    #pragma unroll
    for (int i = 0; i < 4; ++i)
        #pragma unroll
        for (int j = 0; j < 4; ++j) acc[i][j] = f32x4{0.f, 0.f, 0.f, 0.f};

    gl16(gA0, &As[0][(w * 2 + 0) * 512]);
    gl16(gA1, &As[0][(w * 2 + 1) * 512]);
    gl16(gB0, &Bs[0][(w * 2 + 0) * 512]);
    gl16(gB1, &Bs[0][(w * 2 + 1) * 512]);
    __syncthreads();

    for (int kt = 0; kt < 12; ++kt) {
        const int buf = kt & 1;
        if (kt < 11) {
            const int ko = (kt + 1) * 32;
            gl16(gA0 + ko, &As[buf ^ 1][(w * 2 + 0) * 512]);
            gl16(gA1 + ko, &As[buf ^ 1][(w * 2 + 1) * 512]);
            gl16(gB0 + ko, &Bs[buf ^ 1][(w * 2 + 0) * 512]);
            gl16(gB1 + ko, &Bs[buf ^ 1][(w * 2 + 1) * 512]);
        }
        U8 af[4], bf[4];
        #pragma unroll
        for (int f = 0; f < 4; ++f) {
            af[f].u = *(const u32x4*)&As[buf][(wr * 64 + f * 16 + lr) * 32 + lg * 8];
            bf[f].u = *(const u32x4*)&Bs[buf][(wc * 64 + f * 16 + lr) * 32 + lg * 8];
        }
        #pragma unroll
        for (int mf = 0; mf < 4; ++mf)
            #pragma unroll
            for (int nf = 0; nf < 4; ++nf)
                acc[mf][nf] = mfma16(af[mf].s, bf[nf].s, acc[mf][nf]);
        __syncthreads();
    }

    const int tensor = nt / 3;
    u16* dst = (tensor == 0) ? Qb : (tensor == 1) ? Kb : Vb;
    const float scl = (tensor == 0) ? 0.18033688011112042f : 1.0f;   // (1/8)*log2(e) for Q
    const int head_base = (nt % 3) * 2 + wc;
    #pragma unroll
    for (int mf = 0; mf < 4; ++mf)
        #pragma unroll
        for (int nf = 0; nf < 4; ++nf)
            #pragma unroll
            for (int r = 0; r < 4; ++r) {
                int m = m0 + wr * 64 + mf * 16 + lg * 4 + r;
                int b = m >> 11, t = m & 2047;
                int d = nf * 16 + lr;
                dst[((size_t)(b * 6 + head_base) * 2048 + t) * 64 + d] = f2bs(acc[mf][nf][r] * scl);
            }
}

// ---------------- V[bh][t][64] -> Vt[bh][64][pos], key position = per-16 window blocks [0,2,1,3]
__global__ __launch_bounds__(256) void transpose_v(const u16* __restrict__ Vb,
                                                   u16* __restrict__ Vt) {
    __shared__ u16 tile[64][72];
    const int bh = blockIdx.y, t0 = blockIdx.x * 64;
    const int tid = threadIdx.x;
    const int r = tid >> 2, c0 = (tid & 3) * 16;
    const u16* src = Vb + ((size_t)bh * 2048 + t0 + r) * 64 + c0;
    u32x4 a  = *(const u32x4*)(src);
    u32x4 b2 = *(const u32x4*)(src + 8);
    *(u32x4*)&tile[r][c0]     = a;
    *(u32x4*)&tile[r][c0 + 8] = b2;
    __syncthreads();
    struct alignas(16) OutV { u16 v[16]; } ov;
    #pragma unroll
    for (int j = 0; j < 4; ++j) {
        ov.v[j]      = tile[c0 + j][r];
        ov.v[4 + j]  = tile[c0 + 8 + j][r];
        ov.v[8 + j]  = tile[c0 + 4 + j][r];
        ov.v[12 + j] = tile[c0 + 12 + j][r];
    }
    u16* dst = Vt + ((size_t)bh * 64 + r) * 2048 + t0 + c0;
    *(u32x4*)dst       = *(u32x4*)&ov.v[0];
    *(u32x4*)(dst + 8) = *(u32x4*)&ov.v[8];
}

// ---- attn8 compute step: one 32-key tile from this wave's private LDS region
__device__ __forceinline__ void cstep(const char* base, const int koff[4], const int voff[4],
                                      const U8 bq[2][4], f32x16 acc[2][2],
                                      float& rs0, float& rs1) {
    U8 ak0, ak1, ak2, ak3, bv0, bv1, bv2, bv3;
    ak0.u = *(const u32x4*)(base + koff[0]);
    ak1.u = *(const u32x4*)(base + koff[1]);
    ak2.u = *(const u32x4*)(base + koff[2]);
    ak3.u = *(const u32x4*)(base + koff[3]);
    bv0.u = *(const u32x4*)(base + voff[0]);
    bv1.u = *(const u32x4*)(base + voff[1]);
    bv2.u = *(const u32x4*)(base + voff[2]);
    bv3.u = *(const u32x4*)(base + voff[3]);

    f32x16 S0, S1;
    #pragma unroll
    for (int r = 0; r < 16; ++r) { S0[r] = 0.f; S1[r] = 0.f; }
    S0 = mfma32(ak0.s, bq[0][0].s, S0);
    S0 = mfma32(ak1.s, bq[0][1].s, S0);
    S0 = mfma32(ak2.s, bq[0][2].s, S0);
    S0 = mfma32(ak3.s, bq[0][3].s, S0);
    S1 = mfma32(ak0.s, bq[1][0].s, S1);
    S1 = mfma32(ak1.s, bq[1][1].s, S1);
    S1 = mfma32(ak2.s, bq[1][2].s, S1);
    S1 = mfma32(ak3.s, bq[1][3].s, S1);

    float p0[16], p1[16];
    #pragma unroll
    for (int r = 0; r < 16; ++r) { p0[r] = EXP2(S0[r]); p1[r] = EXP2(S1[r]); }
    #pragma unroll
    for (int r = 0; r < 16; ++r) { rs0 += p0[r]; rs1 += p1[r]; }

    U8 pa[2][2];
    #pragma unroll
    for (int i = 0; i < 4; ++i) {
        pa[0][0].uw[i] = cvtpk(p0[2 * i],     p0[2 * i + 1]);
        pa[0][1].uw[i] = cvtpk(p0[8 + 2 * i], p0[9 + 2 * i]);
        pa[1][0].uw[i] = cvtpk(p1[2 * i],     p1[2 * i + 1]);
        pa[1][1].uw[i] = cvtpk(p1[8 + 2 * i], p1[9 + 2 * i]);
    }

    acc[0][0] = mfma32(pa[0][0].s, bv0.s, acc[0][0]);
    acc[0][0] = mfma32(pa[0][1].s, bv1.s, acc[0][0]);
    acc[0][1] = mfma32(pa[0][0].s, bv2.s, acc[0][1]);
    acc[0][1] = mfma32(pa[0][1].s, bv3.s, acc[0][1]);
    acc[1][0] = mfma32(pa[1][0].s, bv0.s, acc[1][0]);
    acc[1][0] = mfma32(pa[1][1].s, bv1.s, acc[1][0]);
    acc[1][1] = mfma32(pa[1][0].s, bv2.s, acc[1][1]);
    acc[1][1] = mfma32(pa[1][1].s, bv3.s, acc[1][1]);
}

// stage one 32-key K/V tile (8 x gl16) into this wave's region at kd
__device__ __forceinline__ void stg8(const u16* ksrc0, const u16* vsrc0, int it, u16* kd) {
    const u16* ks = ksrc0 + it * 2048;
    gl16(ks,        kd);
    gl16(ks + 512,  kd + 512);
    gl16(ks + 1024, kd + 1024);
    gl16(ks + 1536, kd + 1536);
    const u16* vs = vsrc0 + it * 32;
    gl16(vs,         kd + 2048);
    gl16(vs + 32768, kd + 2560);
    gl16(vs + 65536, kd + 3072);
    gl16(vs + 98304, kd + 3584);
}

// ---------------- fused attention v8: wave-private LDS staging, NO in-loop barriers.
// Block = 64 q-rows x 2048 keys, 4 waves; wave = 64q (2 q-subs) x 512-key private quarter.
// K/V double-buffered in wave-private LDS (8KB/wave/buf), counted vmcnt(8) pipeline.
// LDS reads halved vs attn4 (K-frag reused across both q-subs). Merge tree at end.
__global__ __launch_bounds__(256, 2) void attn8(const u16* __restrict__ Qb,
                                                const u16* __restrict__ Kb,
                                                const u16* __restrict__ Vt,
                                                u16* __restrict__ AO) {
    // [2 bufs x 32KB]; per buf, wave wv region at wv*8192: K 4KB (32 rows x 128B,
    // chunk^=(row&7)) then V 4KB (64 d-rows x 64B, chunk^=(row&3))
    __shared__ char smem[65536];
    const int tid = threadIdx.x, wv = tid >> 6, lane = tid & 63;
    const int q = lane & 31, hi = lane >> 5;
    const int bh = blockIdx.x, qt = blockIdx.y;   // grid (24,32) bh-major: XCD-pinned
    const int b = bh / 6, h = bh - b * 6;
    const int qbase = qt * 64;

    // Q B-frags for both q-subs (pre-scaled by (1/8)*log2(e))
    const u16* qp = Qb + ((size_t)bh * 2048 + qbase + q) * 64 + hi * 8;
    U8 bq[2][4];
    #pragma unroll
    for (int qs = 0; qs < 2; ++qs)
        #pragma unroll
        for (int m = 0; m < 4; ++m)
            bq[qs][m].u = *(const u32x4*)(qp + qs * 2048 + m * 16);

    // staging lane addresses (pre-swizzled global sources, linear LDS dest)
    const int l8 = lane >> 3, c8 = lane & 7;
    const u16* ksrc0 = Kb + (size_t)bh * 131072 + (size_t)(wv * 512 + l8) * 64 + (c8 ^ l8) * 8;
    const int lv4 = lane >> 2, c4 = lane & 3;
    const u16* vsrc0 = Vt + (size_t)bh * 131072 + (size_t)lv4 * 2048 + wv * 512 + (c4 ^ (lv4 & 3)) * 8;

    u16* kdA = (u16*)(smem + wv * 8192);
    u16* kdB = (u16*)(smem + 32768 + wv * 8192);
    const char* cbA = smem;
    const char* cbB = smem + 32768;

    // per-lane LDS read offsets (include wave region; buffer base added via cbA/cbB)
    int koff[4], voff[4];
    #pragma unroll
    for (int m = 0; m < 4; ++m)
        koff[m] = wv * 8192 + q * 128 + (((2 * m + hi) ^ (q & 7)) << 4);
    #pragma unroll
    for (int dt2 = 0; dt2 < 2; ++dt2)
        #pragma unroll
        for (int kg = 0; kg < 2; ++kg)
            voff[dt2 * 2 + kg] = wv * 8192 + 4096 + dt2 * 2048 + q * 64 + (((2 * kg + hi) ^ (q & 3)) << 4);

    f32x16 acc[2][2];
    #pragma unroll
    for (int i = 0; i < 2; ++i)
        #pragma unroll
        for (int j = 0; j < 2; ++j)
            #pragma unroll
            for (int r = 0; r < 16; ++r) acc[i][j][r] = 0.f;
    float rs0 = 0.f, rs1 = 0.f;

    stg8(ksrc0, vsrc0, 0, kdA);
    stg8(ksrc0, vsrc0, 1, kdB);

    for (int it2 = 0; it2 < 7; ++it2) {
        VMW8; SB0;                                    // tile 2*it2 landed
        cstep(cbA, koff, voff, bq, acc, rs0, rs1);
        LKW0;                                         // drain reads before overwrite
        stg8(ksrc0, vsrc0, 2 * it2 + 2, kdA);
        VMW8; SB0;                                    // tile 2*it2+1 landed
        cstep(cbB, koff, voff, bq, acc, rs0, rs1);
        LKW0;
        stg8(ksrc0, vsrc0, 2 * it2 + 3, kdB);
    }
    VMW8; SB0; cstep(cbA, koff, voff, bq, acc, rs0, rs1);   // it=14
    VMW0; SB0; cstep(cbB, koff, voff, bq, acc, rs0, rs1);   // it=15

    // rowsum across hi halves
    rs0 += __shfl_xor(rs0, 32, 64);
    rs1 += __shfl_xor(rs1, 32, 64);

    __syncthreads();     // all waves done with K/V LDS before merge reuses it

    // ---- 4-way merge tree over key quarters (identical to verified attn6 epilogue)
    float* r0 = (float*)smem;
    float* r1 = (float*)smem + 4224;

    if (wv == 1) {
        #pragma unroll
        for (int qs = 0; qs < 2; ++qs)
            #pragma unroll
            for (int dt2 = 0; dt2 < 2; ++dt2)
                #pragma unroll
                for (int r = 0; r < 16; ++r) {
                    int row = qs * 32 + (r & 3) + 8 * (r >> 2) + 4 * hi;
                    r0[row * 64 + dt2 * 32 + q] = acc[qs][dt2][r];
                }
        r0[4096 + lane] = rs0; r0[4160 + lane] = rs1;
    } else if (wv == 3) {
        #pragma unroll
        for (int qs = 0; qs < 2; ++qs)
            #pragma unroll
            for (int dt2 = 0; dt2 < 2; ++dt2)
                #pragma unroll
                for (int r = 0; r < 16; ++r) {
                    int row = qs * 32 + (r & 3) + 8 * (r >> 2) + 4 * hi;
                    r1[row * 64 + dt2 * 32 + q] = acc[qs][dt2][r];
                }
        r1[4096 + lane] = rs0; r1[4160 + lane] = rs1;
    }
    __syncthreads();
    if (wv == 0) {
        #pragma unroll
        for (int qs = 0; qs < 2; ++qs)
            #pragma unroll
            for (int dt2 = 0; dt2 < 2; ++dt2)
                #pragma unroll
                for (int r = 0; r < 16; ++r) {
                    int row = qs * 32 + (r & 3) + 8 * (r >> 2) + 4 * hi;
                    acc[qs][dt2][r] += r0[row * 64 + dt2 * 32 + q];
                }
        rs0 += r0[4096 + lane]; rs1 += r0[4160 + lane];
    } else if (wv == 2) {
        #pragma unroll
        for (int qs = 0; qs < 2; ++qs)
            #pragma unroll
            for (int dt2 = 0; dt2 < 2; ++dt2)
                #pragma unroll
                for (int r = 0; r < 16; ++r) {
                    int row = qs * 32 + (r & 3) + 8 * (r >> 2) + 4 * hi;
                    acc[qs][dt2][r] += r1[row * 64 + dt2 * 32 + q];
                }
        rs0 += r1[4096 + lane]; rs1 += r1[4160 + lane];
    }
    __syncthreads();
    if (wv == 2) {
        #pragma unroll
        for (int qs = 0; qs < 2; ++qs)
            #pragma unroll
            for (int dt2 = 0; dt2 < 2; ++dt2)
                #pragma unroll
                for (int r = 0; r < 16; ++r) {
                    int row = qs * 32 + (r & 3) + 8 * (r >> 2) + 4 * hi;
                    r0[row * 64 + dt2 * 32 + q] = acc[qs][dt2][r];
                }
        r0[4096 + lane] = rs0; r0[4160 + lane] = rs1;
    }
    __syncthreads();
    if (wv == 0) {
        #pragma unroll
        for (int qs = 0; qs < 2; ++qs)
            #pragma unroll
            for (int dt2 = 0; dt2 < 2; ++dt2)
                #pragma unroll
                for (int r = 0; r < 16; ++r) {
                    int row = qs * 32 + (r & 3) + 8 * (r >> 2) + 4 * hi;
                    acc[qs][dt2][r] += r0[row * 64 + dt2 * 32 + q];
                }
        rs0 += r0[4096 + lane]; rs1 += r0[4160 + lane];

        const float inv0 = 1.0f / rs0;
        const float inv1 = 1.0f / rs1;
        const size_t aobase = ((size_t)b * 2048 + qbase) * 384 + h * 64;
        #pragma unroll
        for (int qs = 0; qs < 2; ++qs)
            #pragma unroll
            for (int r = 0; r < 16; ++r) {
                const int crow = (r & 3) + 8 * (r >> 2) + 4 * hi;
                const int qrow = qs * 32 + crow;
                float vinv = __shfl(qs == 0 ? inv0 : inv1, crow, 64);
                #pragma unroll
                for (int dt2 = 0; dt2 < 2; ++dt2)
                    AO[aobase + (size_t)qrow * 384 + dt2 * 32 + q] = f2bs(acc[qs][dt2][r] * vinv);
            }
    }
}

// ---------------- output projection: AO[8192,384] @ Wot^T + bo -> out fp32
__global__ __launch_bounds__(256) void outproj2(const u16* __restrict__ AO,
                                                const u16* __restrict__ Wot,
                                                const float* __restrict__ bo,
                                                float* __restrict__ out) {
    __shared__ u16 As[2][64 * 32];
    __shared__ u16 Bs[2][64 * 32];
    const int tid = threadIdx.x, w = tid >> 6, lane = tid & 63;
    const int lr = lane & 15, lg = lane >> 4;
    const int wr = w >> 1, wc = w & 1;
    const int mt = blockIdx.x, nt = blockIdx.y;          // grid (128, 6)
    const int m0 = mt * 64, n0 = nt * 64;

    const int c0 = w * 64 + lane;
    const int ar0 = c0 >> 2, cc0 = c0 & 3;
    const u16* gA = AO  + (size_t)(m0 + ar0) * 384 + cc0 * 8;
    const u16* gB = Wot + (size_t)(n0 + ar0) * 384 + cc0 * 8;

    f32x4 acc[2][2];
    #pragma unroll
    for (int i = 0; i < 2; ++i)
        #pragma unroll
        for (int j = 0; j < 2; ++j) acc[i][j] = f32x4{0.f, 0.f, 0.f, 0.f};

    gl16(gA, &As[0][w * 512]);
    gl16(gB, &Bs[0][w * 512]);
    __syncthreads();

    for (int kt = 0; kt < 12; ++kt) {
        const int buf = kt & 1;
        if (kt < 11) {
            const int ko = (kt + 1) * 32;
            gl16(gA + ko, &As[buf ^ 1][w * 512]);
            gl16(gB + ko, &Bs[buf ^ 1][w * 512]);
        }
        U8 af[2], bf[2];
        #pragma unroll
        for (int f = 0; f < 2; ++f) {
            af[f].u = *(const u32x4*)&As[buf][(wr * 32 + f * 16 + lr) * 32 + lg * 8];
            bf[f].u = *(const u32x4*)&Bs[buf][(wc * 32 + f * 16 + lr) * 32 + lg * 8];
        }
        #pragma unroll
        for (int mf = 0; mf < 2; ++mf)
            #pragma unroll
            for (int nf = 0; nf < 2; ++nf)
                acc[mf][nf] = mfma16(af[mf].s, bf[nf].s, acc[mf][nf]);
        __syncthreads();
    }

    #pragma unroll
    for (int mf = 0; mf < 2; ++mf)
        #pragma unroll
        for (int nf = 0; nf < 2; ++nf) {
            int col = n0 + wc * 32 + nf * 16 + lr;
            float bias = bo[col];
            #pragma unroll
            for (int r = 0; r < 4; ++r) {
                int m = m0 + wr * 32 + mf * 16 + lg * 4 + r;
                out[(size_t)m * 384 + col] = acc[mf][nf][r] + bias;
            }
        }
}

extern "C" void kernel_launch(void* const* d_in, const int* in_sizes, int n_in,
                              void* d_out, int out_size, void* d_ws, size_t ws_size,
                              hipStream_t stream) {
    const float* x  = (const float*)d_in[0];
    const float* Wq = (const float*)d_in[1];
    const float* Wk = (const float*)d_in[2];
    const float* Wv = (const float*)d_in[3];
    const float* Wo = (const float*)d_in[4];
    const float* bo = (const float*)d_in[5];
    float* out = (float*)d_out;
    char* ws = (char*)d_ws;

    u16* Wt  = (u16*)(ws);                    // [1152][384] bf16 (Wq|Wk|Wv heads-major, then Wo^T)
    u16* Wot = (u16*)(ws + 884736);
    u16* xb  = (u16*)(ws + 1179648);          // [8192][384] bf16
    u16* Qb  = (u16*)(ws + 7471104);          // [24][2048][64] bf16
    u16* Kb  = (u16*)(ws + 13762560);
    u16* Vb  = (u16*)(ws + 20054016);
    u16* Vt  = (u16*)(ws + 26345472);         // [24][64][2048] bf16 (key positions permuted)
    u16* AO  = (u16*)(ws + 1179648);          // reuses xb slot (xb dead after proj2)

    pack_w2<<<144, 256, 0, stream>>>(Wq, Wk, Wv, Wo, Wt);
    convert_x<<<1536, 256, 0, stream>>>(x, xb);
    proj2<<<dim3(64, 9), 256, 0, stream>>>(xb, Wt, Qb, Kb, Vb);
    transpose_v<<<dim3(32, 24), 256, 0, stream>>>(Vb, Vt);
    attn8<<<dim3(24, 32), 256, 0, stream>>>(Qb, Kb, Vt, AO);
    outproj2<<<dim3(128, 6), 256, 0, stream>>>(AO, Wot, bo, out);
}